// Round 12
// baseline (223.518 us; speedup 1.0000x reference)
//
#include <hip/hip_runtime.h>
#include <hip/hip_fp8.h>
#include <math.h>

// Problem dims
#define S_   8
#define B_   16
#define D_   10
#define N_   32
#define E_   300
#define H_   128
#define G4_  512
#define SDIM_ 96
#define MID_ 256
#define TOT_ 528

typedef unsigned short u16;
typedef unsigned int u32;
typedef unsigned char u8;
typedef unsigned long long u64;
typedef __attribute__((ext_vector_type(8))) short short8;
typedef __attribute__((ext_vector_type(4))) float f32x4;

// round-to-nearest-even f32 -> bf16
static __device__ __forceinline__ u16 f2bf(float f) {
    unsigned u = __builtin_bit_cast(unsigned, f);
    return (u16)((u + 0x7FFFu + ((u >> 16) & 1u)) >> 16);
}
// f32 -> fp8 e4m3 (OCP) via HIP type (HW cvt on gfx950)
static __device__ __forceinline__ u8 f2fp8(float f) {
    __hip_fp8_e4m3 t(f);
    return (u8)t.__x;
}

// ---------------------------------------------------------------------------
// prep: wpack3[s][ks=47][c=320][q=4][j=8] fp8 e4m3, value = W*16 (scaled into
//       normal range; epilogue multiplies by 1/16). Coalesced via LDS tile.
//       wpre2[s][ks=10][g=512][q=4][j=8] bf16; bcomb; lxwT; lywT; aw1T.
// ---------------------------------------------------------------------------
__global__ __launch_bounds__(256) void prep(
        const float* __restrict__ w3, const float* __restrict__ b3,
        const float* __restrict__ w4, const float* __restrict__ b4,
        const float* __restrict__ w5, const float* __restrict__ b5,
        const float* __restrict__ w_ih,
        const float* __restrict__ lxw, const float* __restrict__ lyw,
        const float* __restrict__ aw1,
        u8* __restrict__ wpack3, u16* __restrict__ wpre2,
        float* __restrict__ bcomb,
        float* __restrict__ lxwT, float* __restrict__ lywT,
        float* __restrict__ aw1T) {
    const int blk = blockIdx.x, tid = threadIdx.x;

    if (blk < 160) {                     // ---- wpack3 (fp8, x16 scale) ----
        __shared__ u8 tile[16][1504];
        const int s = blk / 20, cg = blk % 20;
        for (int i = tid; i < 16 * 376; i += 256)
            reinterpret_cast<u32*>(&tile[0][0])[i] = 0u;
        __syncthreads();
        const int ch = tid >> 4, lane = tid & 15;
        const int c = cg * 16 + ch;
        const float* src = nullptr; int cnt = 0, ktap = 3;
        if (c < 100)      { src = w3 + (size_t)((s * 100 + c      ) * 300) * 3; cnt = 900;  ktap = 3; }
        else if (c < 200) { src = w4 + (size_t)((s * 100 + c - 100) * 300) * 4; cnt = 1200; ktap = 4; }
        else if (c < 300) { src = w5 + (size_t)((s * 100 + c - 200) * 300) * 5; cnt = 1500; ktap = 5; }
        for (int p = lane; p < cnt; p += 16) {
            int e = p / ktap, tap = p - e * ktap;
            tile[ch][tap * 300 + e] = f2fp8(src[p] * 16.0f);
        }
        __syncthreads();
        u16* dst0 = reinterpret_cast<u16*>(wpack3 + (size_t)s * 481280) + cg * 256;
        const int pch = (tid * 2) >> 5, poff = (tid * 2) & 31;
        for (int ks = 0; ks < 47; ++ks) {
            u16 v = (u16)tile[pch][ks * 32 + poff] | ((u16)tile[pch][ks * 32 + poff + 1] << 8);
            dst0[(size_t)ks * 5120 + tid] = v;
        }
    } else if (blk < 416) {              // ---- wpre2 (bf16) ----
        __shared__ u16 tile2[16][320];
        const int u = blk - 160, s = u >> 5, gg = u & 31;
        const int ch = tid >> 4, lane = tid & 15;
        const int g = gg * 16 + ch;
        const float* src = w_ih + (size_t)(s * 512 + g) * 300;
        for (int p = lane; p < 320; p += 16)
            tile2[ch][p] = (p < 300) ? f2bf(src[p]) : (u16)0;
        __syncthreads();
        u32* dst0 = reinterpret_cast<u32*>(wpre2 + (size_t)s * 163840 + gg * 512);
        const int mch = tid >> 4, rem = (tid * 2) & 31;
        for (int ks = 0; ks < 10; ++ks) {
            u32 v = (u32)tile2[mch][ks * 32 + rem] | ((u32)tile2[mch][ks * 32 + rem + 1] << 16);
            dst0[(size_t)ks * 8192 + tid] = v;
        }
    } else if (blk < 872) {              // ---- 32x32 transposes ----
        __shared__ float ldsT[32][33];
        const float* inp; float* outp;
        int inRS, outRS, i0, t0, ivalid = 32;
        if (blk < 672) {
            int u = blk - 416, s = u >> 5, t32 = u & 31;
            int it = t32 >> 2, tt = t32 & 3;
            inp = lxw + (size_t)s * 128 * 256; outp = lxwT + (size_t)s * 256 * 128;
            inRS = 256; outRS = 128; i0 = it * 32; t0 = tt * 32;
        } else if (blk < 736) {
            int u = blk - 672, s = u >> 3, t32 = u & 7;
            int it = t32 >> 1, tt = t32 & 1;
            inp = lyw + (size_t)s * 64 * 128; outp = lywT + (size_t)s * 128 * 64;
            inRS = 128; outRS = 64; i0 = it * 32; t0 = tt * 32;
        } else {
            int u = blk - 736;
            int it = u >> 3, jt = u & 7;
            inp = aw1; outp = aw1T;
            inRS = 528; outRS = 256; i0 = it * 32; t0 = jt * 32;
            ivalid = (i0 + 32 <= 528) ? 32 : (528 - i0);
        }
        const int row = tid >> 3, cf = tid & 7;
        float4 v = make_float4(0.f, 0.f, 0.f, 0.f);
        if (cf * 4 < ivalid)
            v = *reinterpret_cast<const float4*>(inp + (size_t)(t0 + row) * inRS + i0 + cf * 4);
        ldsT[cf * 4 + 0][row] = v.x; ldsT[cf * 4 + 1][row] = v.y;
        ldsT[cf * 4 + 2][row] = v.z; ldsT[cf * 4 + 3][row] = v.w;
        __syncthreads();
        if (row < ivalid) {
            float4 w;
            w.x = ldsT[row][cf * 4 + 0]; w.y = ldsT[row][cf * 4 + 1];
            w.z = ldsT[row][cf * 4 + 2]; w.w = ldsT[row][cf * 4 + 3];
            *reinterpret_cast<float4*>(outp + (size_t)(i0 + row) * outRS + t0 + cf * 4) = w;
        }
    } else {                             // ---- bcomb ----
        for (int i = tid; i < 2560; i += 256) {
            int c = i % 320, s = i / 320;
            float bv = 0.f;
            if (c < 100)      bv = b3[s*100 + c];
            else if (c < 200) bv = b4[s*100 + c - 100];
            else if (c < 300) bv = b5[s*100 + c - 200];
            bcomb[i] = bv;
        }
    }
}

// ---------------------------------------------------------------------------
// conv via fp8 MFMA: block per (s,b,half) = 5 days, 512 thr = 8 waves
// (2m x 4n), wave C[80][80] = 5x5 16x16 tiles, mfma_f32_16x16x32_fp8_fp8.
// A (x, fp8) from LDS window trick; B (w*16, fp8) direct global->VGPR
// coalesced, 2-deep reg prefetch. LDS 67KB -> 2 blocks/CU (4 waves/SIMD).
// Epilogue unscales by 1/16 before bias.
// ---------------------------------------------------------------------------
__global__ __launch_bounds__(512, 4) void conv_mfma(const float* __restrict__ news,
                                                    const u8* __restrict__ wpack3,
                                                    const float* __restrict__ bcomb,
                                                    u16* __restrict__ text_bf) {
    __shared__ u8 xs[5 * 10816];
    __shared__ float part[10][320];
    const int tid = threadIdx.x, bid = blockIdx.x;
    const int s = bid & 7, rr_ = bid >> 3, b = rr_ >> 1, half = rr_ & 1;
    const int l = tid & 63, wvi = tid >> 6;
    const int wm = wvi >> 2, wn = wvi & 3;
    const int q = l >> 4, r16 = l & 15;

    // B-frag pointers: byte = s*481280 + ks*10240 + c*32 + q*8
    const u8* gp[5];
#pragma unroll
    for (int nt = 0; nt < 5; ++nt) {
        int c = wn * 80 + nt * 16 + r16;
        gp[nt] = wpack3 + (size_t)s * 481280 + c * 32 + q * 8;
    }

    u64 bf0[5], bf1[5];
#pragma unroll
    for (int nt = 0; nt < 5; ++nt) bf0[nt] = *reinterpret_cast<const u64*>(gp[nt]);
#pragma unroll
    for (int nt = 0; nt < 5; ++nt) bf1[nt] = *reinterpret_cast<const u64*>(gp[nt] + 10240);

    // stage 5 days f32 -> fp8, 8-deep load batches
    {
        const float4* xg = reinterpret_cast<const float4*>(
            news + (size_t)((b * 8 + s) * 10 + half * 5) * 9600);
        for (int base = 0; base < 12000; base += 4096) {
            float4 v[8];
#pragma unroll
            for (int j = 0; j < 8; ++j) {
                int idx = base + j * 512 + tid;
                if (idx < 12000) v[j] = xg[idx];
            }
#pragma unroll
            for (int j = 0; j < 8; ++j) {
                int idx = base + j * 512 + tid;
                if (idx < 12000) {
                    int day = idx / 2400, rem = idx - day * 2400;
                    u32 o = (u32)f2fp8(v[j].x) | ((u32)f2fp8(v[j].y) << 8)
                          | ((u32)f2fp8(v[j].z) << 16) | ((u32)f2fp8(v[j].w) << 24);
                    *reinterpret_cast<u32*>(&xs[day * 10816 + rem * 4]) = o;
                }
            }
        }
        for (int i = tid; i < 1520; i += 512) {   // zero pads [9600,10816) per day
            int day = i / 304, p = i - day * 304;
            *reinterpret_cast<u32*>(&xs[day * 10816 + 9600 + p * 4]) = 0u;
        }
    }
    __syncthreads();

    f32x4 acc[5][5];
#pragma unroll
    for (int mt = 0; mt < 5; ++mt)
#pragma unroll
        for (int nt = 0; nt < 5; ++nt) acc[mt][nt] = (f32x4)(0.f);

#define LOADA(dst, ks) do {                                                       \
    _Pragma("unroll")                                                             \
    for (int mt_ = 0; mt_ < 5; ++mt_) {                                           \
        int di_ = wm * 5 + mt_;                                                   \
        int off_ = (di_ >> 1) * 10816 + (((di_ & 1) << 4) + r16) * 300            \
                   + (ks) * 32 + q * 8;                                           \
        u32 lo_ = *reinterpret_cast<const u32*>(&xs[off_]);                       \
        u32 hi_ = *reinterpret_cast<const u32*>(&xs[off_ + 4]);                   \
        dst[mt_] = (u64)lo_ | ((u64)hi_ << 32);                                   \
    } } while (0)

#define MFMAS(bfv, av) do {                                                       \
    _Pragma("unroll")                                                             \
    for (int nt_ = 0; nt_ < 5; ++nt_)                                             \
        _Pragma("unroll")                                                         \
        for (int mt_ = 0; mt_ < 5; ++mt_)                                         \
            acc[mt_][nt_] = __builtin_amdgcn_mfma_f32_16x16x32_fp8_fp8(          \
                (long long)av[mt_], (long long)bfv[nt_], acc[mt_][nt_], 0, 0, 0); \
    } while (0)

    for (int ks = 0; ks < 46; ks += 2) {
        u64 a0[5], a1[5];
        LOADA(a0, ks);
        MFMAS(bf0, a0);
#pragma unroll
        for (int nt = 0; nt < 5; ++nt)
            bf0[nt] = *reinterpret_cast<const u64*>(gp[nt] + (ks + 2) * 10240);

        LOADA(a1, ks + 1);
        MFMAS(bf1, a1);
        if (ks + 3 < 47) {
#pragma unroll
            for (int nt = 0; nt < 5; ++nt)
                bf1[nt] = *reinterpret_cast<const u64*>(gp[nt] + (ks + 3) * 10240);
        }
    }
    {
        u64 a0[5];
        LOADA(a0, 46);
        MFMAS(bf0, a0);
    }
#undef LOADA
#undef MFMAS

    // epilogue: masked max -> LDS partials, combine halves; unscale 1/16
#pragma unroll
    for (int mt = 0; mt < 5; ++mt) {
        const int di = wm * 5 + mt;
        const int nwb = (di & 1) << 4;
#pragma unroll
        for (int nt = 0; nt < 5; ++nt) {
            int oc = wn * 80 + nt * 16 + r16;
            int L = (oc < 100) ? 30 : (oc < 200) ? 29 : 28;
            float mx = -3e38f;
#pragma unroll
            for (int rr = 0; rr < 4; ++rr) {
                int nw = nwb + q * 4 + rr;
                if (nw < L) mx = fmaxf(mx, acc[mt][nt][rr]);
            }
            mx = fmaxf(mx, __shfl_xor(mx, 16));
            mx = fmaxf(mx, __shfl_xor(mx, 32));
            if (l < 16) part[di][wn * 80 + nt * 16 + l] = mx;
        }
    }
    __syncthreads();
    for (int i = tid; i < 1600; i += 512) {
        int day = i / 320, oc = i - day * 320;
        float mx = fmaxf(part[2 * day][oc], part[2 * day + 1][oc]);
        text_bf[((size_t)(s * 16 + b) * 10 + half * 5 + day) * 320 + oc] =
            f2bf(mx * 0.0625f + bcomb[s * 320 + oc]);
    }
}

// ---------------------------------------------------------------------------
// stock_tail (unchanged from R11)
// ---------------------------------------------------------------------------
__global__ __launch_bounds__(512) void stock_tail(const u16* __restrict__ text_bf,
                                                  const u16* __restrict__ wpre2,
                                                  const float* __restrict__ b_ih,
                                                  const float* __restrict__ b_hh,
                                                  const float* __restrict__ w_hh,
                                                  const float* __restrict__ lxwT, const float* __restrict__ lxb,
                                                  const float* __restrict__ lywT, const float* __restrict__ lyb,
                                                  float* __restrict__ total) {
    __shared__ u16 as16[16 * 320];
    __shared__ float pre_lds[D_][G4_];
    __shared__ float wchunk[128][129];
    __shared__ float h_lds[H_];
    __shared__ float gates[G4_];
    __shared__ float comb_l[256];
    __shared__ __align__(16) float hx[H_];
    const int sb = blockIdx.x;
    const int s = sb >> 4, b = sb & 15;
    const int t = threadIdx.x, l = t & 63, wv = t >> 6, q = l >> 4, r16 = l & 15;

    for (int i = t; i < 640; i += 512) {
        int r = i / 40, c = i % 40;
        float4 v = make_float4(0.f, 0.f, 0.f, 0.f);
        if (r < D_)
            v = *reinterpret_cast<const float4*>(
                text_bf + ((size_t)((s * 16 + b) * D_ + r)) * 320 + c * 8);
        *reinterpret_cast<float4*>(as16 + r * 320 + ((c ^ (r & 7)) << 3)) = v;
    }
    __syncthreads();

    {
        const u16* gpb[4];
#pragma unroll
        for (int nt = 0; nt < 4; ++nt) {
            int g = wv * 64 + nt * 16 + r16;
            gpb[nt] = wpre2 + (size_t)s * 163840 + g * 32 + q * 8;
        }
        f32x4 acc[4];
#pragma unroll
        for (int nt = 0; nt < 4; ++nt) acc[nt] = (f32x4)(0.f);
        for (int ks = 0; ks < 10; ++ks) {
            short8 a = *reinterpret_cast<const short8*>(
                as16 + r16 * 320 + (((ks * 4 + q) ^ (r16 & 7)) << 3));
#pragma unroll
            for (int nt = 0; nt < 4; ++nt) {
                short8 bf = *reinterpret_cast<const short8*>(gpb[nt] + ks * 16384);
                acc[nt] = __builtin_amdgcn_mfma_f32_16x16x32_bf16(a, bf, acc[nt], 0, 0, 0);
            }
        }
#pragma unroll
        for (int nt = 0; nt < 4; ++nt) {
            int g = wv * 64 + nt * 16 + r16;
            float bias = b_ih[s * G4_ + g] + b_hh[s * G4_ + g];
#pragma unroll
            for (int rr = 0; rr < 4; ++rr) {
                int row = q * 4 + rr;
                if (row < D_) pre_lds[row][g] = acc[nt][rr] + bias;
            }
        }
    }

    float wrs[128];
    for (int c = 0; c < 4; ++c) {
        __syncthreads();
        for (int i2 = t; i2 < 128 * 32; i2 += 512) {
            int row = i2 >> 5, fq = i2 & 31;
            float4 v = *reinterpret_cast<const float4*>(
                w_hh + ((size_t)(s * G4_ + c * 128 + row)) * H_ + fq * 4);
            wchunk[row][fq * 4 + 0] = v.x; wchunk[row][fq * 4 + 1] = v.y;
            wchunk[row][fq * 4 + 2] = v.z; wchunk[row][fq * 4 + 3] = v.w;
        }
        __syncthreads();
        if ((t >> 7) == c) {
            int r = t & 127;
#pragma unroll
            for (int i = 0; i < 128; ++i) wrs[i] = wchunk[r][i];
        }
    }
    __syncthreads();

    float cc = 0.f, hsum = 0.f, hval = 0.f;
    if (t < H_) h_lds[t] = 0.f;
    __syncthreads();

    for (int d = 0; d < D_; ++d) {
        float a0 = pre_lds[d][t];
        float a1 = 0.f, a2 = 0.f, a3 = 0.f;
#pragma unroll
        for (int i = 0; i < 128; i += 4) {
            float4 h4 = *reinterpret_cast<const float4*>(&h_lds[i]);
            a0 = fmaf(wrs[i + 0], h4.x, a0);
            a1 = fmaf(wrs[i + 1], h4.y, a1);
            a2 = fmaf(wrs[i + 2], h4.z, a2);
            a3 = fmaf(wrs[i + 3], h4.w, a3);
        }
        gates[t] = (a0 + a1) + (a2 + a3);
        __syncthreads();
        if (t < H_) {
            float ig = 1.f / (1.f + expf(-gates[t]));
            float fg = 1.f / (1.f + expf(-gates[H_ + t]));
            float gg = tanhf(gates[2 * H_ + t]);
            float og = 1.f / (1.f + expf(-gates[3 * H_ + t]));
            cc = fg * cc + ig * gg;
            hval = og * tanhf(cc);
            hsum += hval;
            h_lds[t] = hval;
        }
        __syncthreads();
    }
    if (t < H_) { comb_l[t] = hval; comb_l[H_ + t] = hsum; }
    __syncthreads();
    if (t < H_) {
        const float* wvp = lxwT + (size_t)s * 256 * 128 + t;
        float a0 = lxb[s * H_ + t], a1 = 0.f;
        for (int i = 0; i < 256; i += 2) {
            a0 = fmaf(comb_l[i], wvp[(size_t)i * 128], a0);
            a1 = fmaf(comb_l[i + 1], wvp[(size_t)(i + 1) * 128], a1);
        }
        hx[t] = fmaxf(a0 + a1, 0.f);
    }
    __syncthreads();
    if (t < 64) {
        const float* wvp = lywT + (size_t)s * 128 * 64 + t;
        float a0 = lyb[s * 64 + t], a1 = 0.f;
        for (int i = 0; i < 128; i += 2) {
            a0 = fmaf(hx[i], wvp[(size_t)i * 64], a0);
            a1 = fmaf(hx[i + 1], wvp[(size_t)(i + 1) * 64], a1);
        }
        total[(size_t)b * 512 + s * 64 + t] = fmaxf(a0 + a1, 0.f);
    }
}

// ---------------------------------------------------------------------------
// head_feats (unchanged)
// ---------------------------------------------------------------------------
__global__ __launch_bounds__(512) void head_feats(const float* __restrict__ total,
                                                  const float* __restrict__ sf,
                                                  const float* __restrict__ w1, const float* __restrict__ b1,
                                                  const float* __restrict__ w2, const float* __restrict__ b2,
                                                  const float* __restrict__ aw1T, const float* __restrict__ ab1,
                                                  const float* __restrict__ aw2, const float* __restrict__ ab2,
                                                  const float* __restrict__ avar,
                                                  float* __restrict__ out) {
    __shared__ __align__(16) float tr[TOT_];
    __shared__ float hid[MID_];
    __shared__ float h1f[24];
    __shared__ float pA[MID_], pB[MID_];
    const int bb = blockIdx.x, t = threadIdx.x;
    if (t < 128)
        reinterpret_cast<float4*>(tr)[t] = reinterpret_cast<const float4*>(total + (size_t)bb * 512)[t];
    if (t < 24) {
        float acc = b1[t];
        for (int i = 0; i < SDIM_; ++i) acc = fmaf(sf[bb * SDIM_ + i], w1[t * SDIM_ + i], acc);
        h1f[t] = fmaxf(acc, 0.f);
    }
    __syncthreads();
    if (t < 16) {
        float acc = b2[t];
        for (int i = 0; i < 24; ++i) acc = fmaf(h1f[i], w2[t * 24 + i], acc);
        tr[512 + t] = acc;
    }
    __syncthreads();
    {
        const int j = t & 255, hf = t >> 8;
        const int ilo = hf ? 264 : 0, ihi = hf ? 528 : 264;
        const float* wv = aw1T + j;
        float a0 = 0.f, a1 = 0.f, a2 = 0.f, a3 = 0.f;
        for (int i = ilo; i < ihi; i += 4) {
            a0 = fmaf(tr[i + 0], wv[(size_t)(i + 0) * 256], a0);
            a1 = fmaf(tr[i + 1], wv[(size_t)(i + 1) * 256], a1);
            a2 = fmaf(tr[i + 2], wv[(size_t)(i + 2) * 256], a2);
            a3 = fmaf(tr[i + 3], wv[(size_t)(i + 3) * 256], a3);
        }
        float p = (a0 + a1) + (a2 + a3);
        if (hf) pB[j] = p; else pA[j] = p;
    }
    __syncthreads();
    if (t < MID_) hid[t] = fmaxf(pA[t] + pB[t] + ab1[t], 0.f);
    __syncthreads();
    if (t < 8) {
        float acc = ab2[t];
        const float* wv = aw2 + (size_t)t * MID_;
        for (int i = 0; i < MID_; ++i) acc = fmaf(hid[i], wv[i], acc);
        out[bb * 8 + t] = tanhf(acc);
    }
    if (bb == 0 && t >= 8 && t < 16) out[128 + (t - 8)] = expf(avar[t - 8]);
}

// ---------------------------------------------------------------------------
extern "C" void kernel_launch(void* const* d_in, const int* in_sizes, int n_in,
                              void* d_out, int out_size, void* d_ws, size_t ws_size,
                              hipStream_t stream) {
    const float* news = (const float*)d_in[0];
    const float* sf   = (const float*)d_in[1];
    const float* w3   = (const float*)d_in[2];  const float* b3 = (const float*)d_in[3];
    const float* w4   = (const float*)d_in[4];  const float* b4 = (const float*)d_in[5];
    const float* w5   = (const float*)d_in[6];  const float* b5 = (const float*)d_in[7];
    const float* w_ih = (const float*)d_in[8];  const float* w_hh = (const float*)d_in[9];
    const float* b_ih = (const float*)d_in[10]; const float* b_hh = (const float*)d_in[11];
    const float* lxw  = (const float*)d_in[12]; const float* lxb = (const float*)d_in[13];
    const float* lyw  = (const float*)d_in[14]; const float* lyb = (const float*)d_in[15];
    const float* w1   = (const float*)d_in[16]; const float* b1 = (const float*)d_in[17];
    const float* w2   = (const float*)d_in[18]; const float* b2 = (const float*)d_in[19];
    const float* aw1  = (const float*)d_in[20]; const float* ab1 = (const float*)d_in[21];
    const float* aw2  = (const float*)d_in[22]; const float* ab2 = (const float*)d_in[23];
    const float* avar = (const float*)d_in[24];

    char* ws = (char*)d_ws;
    u8*    wpack3  = (u8*)ws;                                   // 3,850,240 B
    u16*   wpre2   = (u16*)(ws + 3850240);                      // 2,621,440 B
    float* bcomb   = (float*)(ws + 6471680);                    // 10,240 B
    u16*   text_bf = (u16*)(ws + 6481920);                      // 819,200 B
    float* total   = (float*)(ws + 7301120);                    // 32,768 B
    float* lxwT    = (float*)(ws + 7333888);                    // 1,048,576 B
    float* lywT    = (float*)(ws + 8382464);                    // 262,144 B
    float* aw1T    = (float*)(ws + 8644608);                    // 540,672 B (end ~9.2 MB)

    prep<<<873, 256, 0, stream>>>(w3, b3, w4, b4, w5, b5, w_ih, lxw, lyw, aw1,
                                  wpack3, wpre2, bcomb, lxwT, lywT, aw1T);
    conv_mfma<<<256, 512, 0, stream>>>(news, wpack3, bcomb, text_bf);
    stock_tail<<<S_ * B_, 512, 0, stream>>>(text_bf, wpre2, b_ih, b_hh, w_hh,
                                            lxwT, lxb, lywT, lyb, total);
    head_feats<<<B_, 512, 0, stream>>>(total, sf, w1, b1, w2, b2, aw1T, ab1, aw2, ab2, avar, (float*)d_out);
}

// Round 13
// 135.608 us; speedup vs baseline: 1.6483x; 1.6483x over previous
//
#include <hip/hip_runtime.h>
#include <hip/hip_fp8.h>
#include <math.h>

// Problem dims
#define S_   8
#define B_   16
#define D_   10
#define N_   32
#define E_   300
#define H_   128
#define G4_  512
#define SDIM_ 96
#define MID_ 256
#define TOT_ 528

typedef unsigned short u16;
typedef unsigned int u32;
typedef unsigned char u8;
typedef unsigned long long u64;
typedef __attribute__((ext_vector_type(8))) short short8;
typedef __attribute__((ext_vector_type(4))) float f32x4;

// round-to-nearest-even f32 -> bf16
static __device__ __forceinline__ u16 f2bf(float f) {
    unsigned u = __builtin_bit_cast(unsigned, f);
    return (u16)((u + 0x7FFFu + ((u >> 16) & 1u)) >> 16);
}
// f32 -> fp8 e4m3 (OCP) via HIP type (HW cvt on gfx950)
static __device__ __forceinline__ u8 f2fp8(float f) {
    __hip_fp8_e4m3 t(f);
    return (u8)t.__x;
}

// ---------------------------------------------------------------------------
// prep (unchanged from R12): wpack3 fp8 x16-scaled, wpre2 bf16, bcomb,
// lxwT, lywT, aw1T. 873 blocks x 256.
// ---------------------------------------------------------------------------
__global__ __launch_bounds__(256) void prep(
        const float* __restrict__ w3, const float* __restrict__ b3,
        const float* __restrict__ w4, const float* __restrict__ b4,
        const float* __restrict__ w5, const float* __restrict__ b5,
        const float* __restrict__ w_ih,
        const float* __restrict__ lxw, const float* __restrict__ lyw,
        const float* __restrict__ aw1,
        u8* __restrict__ wpack3, u16* __restrict__ wpre2,
        float* __restrict__ bcomb,
        float* __restrict__ lxwT, float* __restrict__ lywT,
        float* __restrict__ aw1T) {
    const int blk = blockIdx.x, tid = threadIdx.x;

    if (blk < 160) {                     // ---- wpack3 (fp8, x16 scale) ----
        __shared__ u8 tile[16][1504];
        const int s = blk / 20, cg = blk % 20;
        for (int i = tid; i < 16 * 376; i += 256)
            reinterpret_cast<u32*>(&tile[0][0])[i] = 0u;
        __syncthreads();
        const int ch = tid >> 4, lane = tid & 15;
        const int c = cg * 16 + ch;
        const float* src = nullptr; int cnt = 0, ktap = 3;
        if (c < 100)      { src = w3 + (size_t)((s * 100 + c      ) * 300) * 3; cnt = 900;  ktap = 3; }
        else if (c < 200) { src = w4 + (size_t)((s * 100 + c - 100) * 300) * 4; cnt = 1200; ktap = 4; }
        else if (c < 300) { src = w5 + (size_t)((s * 100 + c - 200) * 300) * 5; cnt = 1500; ktap = 5; }
        for (int p = lane; p < cnt; p += 16) {
            int e = p / ktap, tap = p - e * ktap;
            tile[ch][tap * 300 + e] = f2fp8(src[p] * 16.0f);
        }
        __syncthreads();
        u16* dst0 = reinterpret_cast<u16*>(wpack3 + (size_t)s * 481280) + cg * 256;
        const int pch = (tid * 2) >> 5, poff = (tid * 2) & 31;
        for (int ks = 0; ks < 47; ++ks) {
            u16 v = (u16)tile[pch][ks * 32 + poff] | ((u16)tile[pch][ks * 32 + poff + 1] << 8);
            dst0[(size_t)ks * 5120 + tid] = v;
        }
    } else if (blk < 416) {              // ---- wpre2 (bf16) ----
        __shared__ u16 tile2[16][320];
        const int u = blk - 160, s = u >> 5, gg = u & 31;
        const int ch = tid >> 4, lane = tid & 15;
        const int g = gg * 16 + ch;
        const float* src = w_ih + (size_t)(s * 512 + g) * 300;
        for (int p = lane; p < 320; p += 16)
            tile2[ch][p] = (p < 300) ? f2bf(src[p]) : (u16)0;
        __syncthreads();
        u32* dst0 = reinterpret_cast<u32*>(wpre2 + (size_t)s * 163840 + gg * 512);
        const int mch = tid >> 4, rem = (tid * 2) & 31;
        for (int ks = 0; ks < 10; ++ks) {
            u32 v = (u32)tile2[mch][ks * 32 + rem] | ((u32)tile2[mch][ks * 32 + rem + 1] << 16);
            dst0[(size_t)ks * 8192 + tid] = v;
        }
    } else if (blk < 872) {              // ---- 32x32 transposes ----
        __shared__ float ldsT[32][33];
        const float* inp; float* outp;
        int inRS, outRS, i0, t0, ivalid = 32;
        if (blk < 672) {
            int u = blk - 416, s = u >> 5, t32 = u & 31;
            int it = t32 >> 2, tt = t32 & 3;
            inp = lxw + (size_t)s * 128 * 256; outp = lxwT + (size_t)s * 256 * 128;
            inRS = 256; outRS = 128; i0 = it * 32; t0 = tt * 32;
        } else if (blk < 736) {
            int u = blk - 672, s = u >> 3, t32 = u & 7;
            int it = t32 >> 1, tt = t32 & 1;
            inp = lyw + (size_t)s * 64 * 128; outp = lywT + (size_t)s * 128 * 64;
            inRS = 128; outRS = 64; i0 = it * 32; t0 = tt * 32;
        } else {
            int u = blk - 736;
            int it = u >> 3, jt = u & 7;
            inp = aw1; outp = aw1T;
            inRS = 528; outRS = 256; i0 = it * 32; t0 = jt * 32;
            ivalid = (i0 + 32 <= 528) ? 32 : (528 - i0);
        }
        const int row = tid >> 3, cf = tid & 7;
        float4 v = make_float4(0.f, 0.f, 0.f, 0.f);
        if (cf * 4 < ivalid)
            v = *reinterpret_cast<const float4*>(inp + (size_t)(t0 + row) * inRS + i0 + cf * 4);
        ldsT[cf * 4 + 0][row] = v.x; ldsT[cf * 4 + 1][row] = v.y;
        ldsT[cf * 4 + 2][row] = v.z; ldsT[cf * 4 + 3][row] = v.w;
        __syncthreads();
        if (row < ivalid) {
            float4 w;
            w.x = ldsT[row][cf * 4 + 0]; w.y = ldsT[row][cf * 4 + 1];
            w.z = ldsT[row][cf * 4 + 2]; w.w = ldsT[row][cf * 4 + 3];
            *reinterpret_cast<float4*>(outp + (size_t)(i0 + row) * outRS + t0 + cf * 4) = w;
        }
    } else {                             // ---- bcomb ----
        for (int i = tid; i < 2560; i += 256) {
            int c = i % 320, s = i / 320;
            float bv = 0.f;
            if (c < 100)      bv = b3[s*100 + c];
            else if (c < 200) bv = b4[s*100 + c - 100];
            else if (c < 300) bv = b5[s*100 + c - 200];
            bcomb[i] = bv;
        }
    }
}

// ---------------------------------------------------------------------------
// conv via fp8 MFMA: block per (s,b,half) = 5 days, 512 thr = 8 waves
// (2m x 4n), wave C[80][80] = 5x5 16x16 tiles, mfma_f32_16x16x32_fp8_fp8.
// A (x, fp8) from LDS window trick; B (w*16, fp8) direct global->VGPR
// coalesced, 2-deep reg prefetch. launch_bounds(512,1): VGPR cap 256,
// NO SPILL (R12's (512,4) forced 64 VGPR -> acc spilled to scratch,
// 74MB scratch writes, 2.6x regression).
// ---------------------------------------------------------------------------
__global__ __launch_bounds__(512, 1) void conv_mfma(const float* __restrict__ news,
                                                    const u8* __restrict__ wpack3,
                                                    const float* __restrict__ bcomb,
                                                    u16* __restrict__ text_bf) {
    __shared__ u8 xs[5 * 10816];
    __shared__ float part[10][320];
    const int tid = threadIdx.x, bid = blockIdx.x;
    const int s = bid & 7, rr_ = bid >> 3, b = rr_ >> 1, half = rr_ & 1;
    const int l = tid & 63, wvi = tid >> 6;
    const int wm = wvi >> 2, wn = wvi & 3;
    const int q = l >> 4, r16 = l & 15;

    // B-frag pointers: byte = s*481280 + ks*10240 + c*32 + q*8
    const u8* gp[5];
#pragma unroll
    for (int nt = 0; nt < 5; ++nt) {
        int c = wn * 80 + nt * 16 + r16;
        gp[nt] = wpack3 + (size_t)s * 481280 + c * 32 + q * 8;
    }

    u64 bf0[5], bf1[5];
#pragma unroll
    for (int nt = 0; nt < 5; ++nt) bf0[nt] = *reinterpret_cast<const u64*>(gp[nt]);
#pragma unroll
    for (int nt = 0; nt < 5; ++nt) bf1[nt] = *reinterpret_cast<const u64*>(gp[nt] + 10240);

    // stage 5 days f32 -> fp8, 8-deep load batches
    {
        const float4* xg = reinterpret_cast<const float4*>(
            news + (size_t)((b * 8 + s) * 10 + half * 5) * 9600);
        for (int base = 0; base < 12000; base += 4096) {
            float4 v[8];
#pragma unroll
            for (int j = 0; j < 8; ++j) {
                int idx = base + j * 512 + tid;
                if (idx < 12000) v[j] = xg[idx];
            }
#pragma unroll
            for (int j = 0; j < 8; ++j) {
                int idx = base + j * 512 + tid;
                if (idx < 12000) {
                    int day = idx / 2400, rem = idx - day * 2400;
                    u32 o = (u32)f2fp8(v[j].x) | ((u32)f2fp8(v[j].y) << 8)
                          | ((u32)f2fp8(v[j].z) << 16) | ((u32)f2fp8(v[j].w) << 24);
                    *reinterpret_cast<u32*>(&xs[day * 10816 + rem * 4]) = o;
                }
            }
        }
        for (int i = tid; i < 1520; i += 512) {   // zero pads [9600,10816) per day
            int day = i / 304, p = i - day * 304;
            *reinterpret_cast<u32*>(&xs[day * 10816 + 9600 + p * 4]) = 0u;
        }
    }
    __syncthreads();

    f32x4 acc[5][5];
#pragma unroll
    for (int mt = 0; mt < 5; ++mt)
#pragma unroll
        for (int nt = 0; nt < 5; ++nt) acc[mt][nt] = (f32x4)(0.f);

#define LOADA(dst, ks) do {                                                       \
    _Pragma("unroll")                                                             \
    for (int mt_ = 0; mt_ < 5; ++mt_) {                                           \
        int di_ = wm * 5 + mt_;                                                   \
        int off_ = (di_ >> 1) * 10816 + (((di_ & 1) << 4) + r16) * 300            \
                   + (ks) * 32 + q * 8;                                           \
        u32 lo_ = *reinterpret_cast<const u32*>(&xs[off_]);                       \
        u32 hi_ = *reinterpret_cast<const u32*>(&xs[off_ + 4]);                   \
        dst[mt_] = (u64)lo_ | ((u64)hi_ << 32);                                   \
    } } while (0)

#define MFMAS(bfv, av) do {                                                       \
    _Pragma("unroll")                                                             \
    for (int nt_ = 0; nt_ < 5; ++nt_)                                             \
        _Pragma("unroll")                                                         \
        for (int mt_ = 0; mt_ < 5; ++mt_)                                         \
            acc[mt_][nt_] = __builtin_amdgcn_mfma_f32_16x16x32_fp8_fp8(          \
                (long long)av[mt_], (long long)bfv[nt_], acc[mt_][nt_], 0, 0, 0); \
    } while (0)

    for (int ks = 0; ks < 46; ks += 2) {
        u64 a0[5], a1[5];
        LOADA(a0, ks);
        MFMAS(bf0, a0);
#pragma unroll
        for (int nt = 0; nt < 5; ++nt)
            bf0[nt] = *reinterpret_cast<const u64*>(gp[nt] + (ks + 2) * 10240);

        LOADA(a1, ks + 1);
        MFMAS(bf1, a1);
        if (ks + 3 < 47) {
#pragma unroll
            for (int nt = 0; nt < 5; ++nt)
                bf1[nt] = *reinterpret_cast<const u64*>(gp[nt] + (ks + 3) * 10240);
        }
    }
    {
        u64 a0[5];
        LOADA(a0, 46);
        MFMAS(bf0, a0);
    }
#undef LOADA
#undef MFMAS

    // epilogue: masked max -> LDS partials, combine halves; unscale 1/16
#pragma unroll
    for (int mt = 0; mt < 5; ++mt) {
        const int di = wm * 5 + mt;
        const int nwb = (di & 1) << 4;
#pragma unroll
        for (int nt = 0; nt < 5; ++nt) {
            int oc = wn * 80 + nt * 16 + r16;
            int L = (oc < 100) ? 30 : (oc < 200) ? 29 : 28;
            float mx = -3e38f;
#pragma unroll
            for (int rr = 0; rr < 4; ++rr) {
                int nw = nwb + q * 4 + rr;
                if (nw < L) mx = fmaxf(mx, acc[mt][nt][rr]);
            }
            mx = fmaxf(mx, __shfl_xor(mx, 16));
            mx = fmaxf(mx, __shfl_xor(mx, 32));
            if (l < 16) part[di][wn * 80 + nt * 16 + l] = mx;
        }
    }
    __syncthreads();
    for (int i = tid; i < 1600; i += 512) {
        int day = i / 320, oc = i - day * 320;
        float mx = fmaxf(part[2 * day][oc], part[2 * day + 1][oc]);
        text_bf[((size_t)(s * 16 + b) * 10 + half * 5 + day) * 320 + oc] =
            f2bf(mx * 0.0625f + bcomb[s * 320 + oc]);
    }
}

// ---------------------------------------------------------------------------
// stock_tail (unchanged from R11)
// ---------------------------------------------------------------------------
__global__ __launch_bounds__(512) void stock_tail(const u16* __restrict__ text_bf,
                                                  const u16* __restrict__ wpre2,
                                                  const float* __restrict__ b_ih,
                                                  const float* __restrict__ b_hh,
                                                  const float* __restrict__ w_hh,
                                                  const float* __restrict__ lxwT, const float* __restrict__ lxb,
                                                  const float* __restrict__ lywT, const float* __restrict__ lyb,
                                                  float* __restrict__ total) {
    __shared__ u16 as16[16 * 320];
    __shared__ float pre_lds[D_][G4_];
    __shared__ float wchunk[128][129];
    __shared__ float h_lds[H_];
    __shared__ float gates[G4_];
    __shared__ float comb_l[256];
    __shared__ __align__(16) float hx[H_];
    const int sb = blockIdx.x;
    const int s = sb >> 4, b = sb & 15;
    const int t = threadIdx.x, l = t & 63, wv = t >> 6, q = l >> 4, r16 = l & 15;

    for (int i = t; i < 640; i += 512) {
        int r = i / 40, c = i % 40;
        float4 v = make_float4(0.f, 0.f, 0.f, 0.f);
        if (r < D_)
            v = *reinterpret_cast<const float4*>(
                text_bf + ((size_t)((s * 16 + b) * D_ + r)) * 320 + c * 8);
        *reinterpret_cast<float4*>(as16 + r * 320 + ((c ^ (r & 7)) << 3)) = v;
    }
    __syncthreads();

    {
        const u16* gpb[4];
#pragma unroll
        for (int nt = 0; nt < 4; ++nt) {
            int g = wv * 64 + nt * 16 + r16;
            gpb[nt] = wpre2 + (size_t)s * 163840 + g * 32 + q * 8;
        }
        f32x4 acc[4];
#pragma unroll
        for (int nt = 0; nt < 4; ++nt) acc[nt] = (f32x4)(0.f);
        for (int ks = 0; ks < 10; ++ks) {
            short8 a = *reinterpret_cast<const short8*>(
                as16 + r16 * 320 + (((ks * 4 + q) ^ (r16 & 7)) << 3));
#pragma unroll
            for (int nt = 0; nt < 4; ++nt) {
                short8 bf = *reinterpret_cast<const short8*>(gpb[nt] + ks * 16384);
                acc[nt] = __builtin_amdgcn_mfma_f32_16x16x32_bf16(a, bf, acc[nt], 0, 0, 0);
            }
        }
#pragma unroll
        for (int nt = 0; nt < 4; ++nt) {
            int g = wv * 64 + nt * 16 + r16;
            float bias = b_ih[s * G4_ + g] + b_hh[s * G4_ + g];
#pragma unroll
            for (int rr = 0; rr < 4; ++rr) {
                int row = q * 4 + rr;
                if (row < D_) pre_lds[row][g] = acc[nt][rr] + bias;
            }
        }
    }

    float wrs[128];
    for (int c = 0; c < 4; ++c) {
        __syncthreads();
        for (int i2 = t; i2 < 128 * 32; i2 += 512) {
            int row = i2 >> 5, fq = i2 & 31;
            float4 v = *reinterpret_cast<const float4*>(
                w_hh + ((size_t)(s * G4_ + c * 128 + row)) * H_ + fq * 4);
            wchunk[row][fq * 4 + 0] = v.x; wchunk[row][fq * 4 + 1] = v.y;
            wchunk[row][fq * 4 + 2] = v.z; wchunk[row][fq * 4 + 3] = v.w;
        }
        __syncthreads();
        if ((t >> 7) == c) {
            int r = t & 127;
#pragma unroll
            for (int i = 0; i < 128; ++i) wrs[i] = wchunk[r][i];
        }
    }
    __syncthreads();

    float cc = 0.f, hsum = 0.f, hval = 0.f;
    if (t < H_) h_lds[t] = 0.f;
    __syncthreads();

    for (int d = 0; d < D_; ++d) {
        float a0 = pre_lds[d][t];
        float a1 = 0.f, a2 = 0.f, a3 = 0.f;
#pragma unroll
        for (int i = 0; i < 128; i += 4) {
            float4 h4 = *reinterpret_cast<const float4*>(&h_lds[i]);
            a0 = fmaf(wrs[i + 0], h4.x, a0);
            a1 = fmaf(wrs[i + 1], h4.y, a1);
            a2 = fmaf(wrs[i + 2], h4.z, a2);
            a3 = fmaf(wrs[i + 3], h4.w, a3);
        }
        gates[t] = (a0 + a1) + (a2 + a3);
        __syncthreads();
        if (t < H_) {
            float ig = 1.f / (1.f + expf(-gates[t]));
            float fg = 1.f / (1.f + expf(-gates[H_ + t]));
            float gg = tanhf(gates[2 * H_ + t]);
            float og = 1.f / (1.f + expf(-gates[3 * H_ + t]));
            cc = fg * cc + ig * gg;
            hval = og * tanhf(cc);
            hsum += hval;
            h_lds[t] = hval;
        }
        __syncthreads();
    }
    if (t < H_) { comb_l[t] = hval; comb_l[H_ + t] = hsum; }
    __syncthreads();
    if (t < H_) {
        const float* wvp = lxwT + (size_t)s * 256 * 128 + t;
        float a0 = lxb[s * H_ + t], a1 = 0.f;
        for (int i = 0; i < 256; i += 2) {
            a0 = fmaf(comb_l[i], wvp[(size_t)i * 128], a0);
            a1 = fmaf(comb_l[i + 1], wvp[(size_t)(i + 1) * 128], a1);
        }
        hx[t] = fmaxf(a0 + a1, 0.f);
    }
    __syncthreads();
    if (t < 64) {
        const float* wvp = lywT + (size_t)s * 128 * 64 + t;
        float a0 = lyb[s * 64 + t], a1 = 0.f;
        for (int i = 0; i < 128; i += 2) {
            a0 = fmaf(hx[i], wvp[(size_t)i * 64], a0);
            a1 = fmaf(hx[i + 1], wvp[(size_t)(i + 1) * 64], a1);
        }
        total[(size_t)b * 512 + s * 64 + t] = fmaxf(a0 + a1, 0.f);
    }
}

// ---------------------------------------------------------------------------
// head_feats (unchanged)
// ---------------------------------------------------------------------------
__global__ __launch_bounds__(512) void head_feats(const float* __restrict__ total,
                                                  const float* __restrict__ sf,
                                                  const float* __restrict__ w1, const float* __restrict__ b1,
                                                  const float* __restrict__ w2, const float* __restrict__ b2,
                                                  const float* __restrict__ aw1T, const float* __restrict__ ab1,
                                                  const float* __restrict__ aw2, const float* __restrict__ ab2,
                                                  const float* __restrict__ avar,
                                                  float* __restrict__ out) {
    __shared__ __align__(16) float tr[TOT_];
    __shared__ float hid[MID_];
    __shared__ float h1f[24];
    __shared__ float pA[MID_], pB[MID_];
    const int bb = blockIdx.x, t = threadIdx.x;
    if (t < 128)
        reinterpret_cast<float4*>(tr)[t] = reinterpret_cast<const float4*>(total + (size_t)bb * 512)[t];
    if (t < 24) {
        float acc = b1[t];
        for (int i = 0; i < SDIM_; ++i) acc = fmaf(sf[bb * SDIM_ + i], w1[t * SDIM_ + i], acc);
        h1f[t] = fmaxf(acc, 0.f);
    }
    __syncthreads();
    if (t < 16) {
        float acc = b2[t];
        for (int i = 0; i < 24; ++i) acc = fmaf(h1f[i], w2[t * 24 + i], acc);
        tr[512 + t] = acc;
    }
    __syncthreads();
    {
        const int j = t & 255, hf = t >> 8;
        const int ilo = hf ? 264 : 0, ihi = hf ? 528 : 264;
        const float* wv = aw1T + j;
        float a0 = 0.f, a1 = 0.f, a2 = 0.f, a3 = 0.f;
        for (int i = ilo; i < ihi; i += 4) {
            a0 = fmaf(tr[i + 0], wv[(size_t)(i + 0) * 256], a0);
            a1 = fmaf(tr[i + 1], wv[(size_t)(i + 1) * 256], a1);
            a2 = fmaf(tr[i + 2], wv[(size_t)(i + 2) * 256], a2);
            a3 = fmaf(tr[i + 3], wv[(size_t)(i + 3) * 256], a3);
        }
        float p = (a0 + a1) + (a2 + a3);
        if (hf) pB[j] = p; else pA[j] = p;
    }
    __syncthreads();
    if (t < MID_) hid[t] = fmaxf(pA[t] + pB[t] + ab1[t], 0.f);
    __syncthreads();
    if (t < 8) {
        float acc = ab2[t];
        const float* wv = aw2 + (size_t)t * MID_;
        for (int i = 0; i < MID_; ++i) acc = fmaf(hid[i], wv[i], acc);
        out[bb * 8 + t] = tanhf(acc);
    }
    if (bb == 0 && t >= 8 && t < 16) out[128 + (t - 8)] = expf(avar[t - 8]);
}

// ---------------------------------------------------------------------------
extern "C" void kernel_launch(void* const* d_in, const int* in_sizes, int n_in,
                              void* d_out, int out_size, void* d_ws, size_t ws_size,
                              hipStream_t stream) {
    const float* news = (const float*)d_in[0];
    const float* sf   = (const float*)d_in[1];
    const float* w3   = (const float*)d_in[2];  const float* b3 = (const float*)d_in[3];
    const float* w4   = (const float*)d_in[4];  const float* b4 = (const float*)d_in[5];
    const float* w5   = (const float*)d_in[6];  const float* b5 = (const float*)d_in[7];
    const float* w_ih = (const float*)d_in[8];  const float* w_hh = (const float*)d_in[9];
    const float* b_ih = (const float*)d_in[10]; const float* b_hh = (const float*)d_in[11];
    const float* lxw  = (const float*)d_in[12]; const float* lxb = (const float*)d_in[13];
    const float* lyw  = (const float*)d_in[14]; const float* lyb = (const float*)d_in[15];
    const float* w1   = (const float*)d_in[16]; const float* b1 = (const float*)d_in[17];
    const float* w2   = (const float*)d_in[18]; const float* b2 = (const float*)d_in[19];
    const float* aw1  = (const float*)d_in[20]; const float* ab1 = (const float*)d_in[21];
    const float* aw2  = (const float*)d_in[22]; const float* ab2 = (const float*)d_in[23];
    const float* avar = (const float*)d_in[24];

    char* ws = (char*)d_ws;
    u8*    wpack3  = (u8*)ws;                                   // 3,850,240 B
    u16*   wpre2   = (u16*)(ws + 3850240);                      // 2,621,440 B
    float* bcomb   = (float*)(ws + 6471680);                    // 10,240 B
    u16*   text_bf = (u16*)(ws + 6481920);                      // 819,200 B
    float* total   = (float*)(ws + 7301120);                    // 32,768 B
    float* lxwT    = (float*)(ws + 7333888);                    // 1,048,576 B
    float* lywT    = (float*)(ws + 8382464);                    // 262,144 B
    float* aw1T    = (float*)(ws + 8644608);                    // 540,672 B (end ~9.2 MB)

    prep<<<873, 256, 0, stream>>>(w3, b3, w4, b4, w5, b5, w_ih, lxw, lyw, aw1,
                                  wpack3, wpre2, bcomb, lxwT, lywT, aw1T);
    conv_mfma<<<256, 512, 0, stream>>>(news, wpack3, bcomb, text_bf);
    stock_tail<<<S_ * B_, 512, 0, stream>>>(text_bf, wpre2, b_ih, b_hh, w_hh,
                                            lxwT, lxb, lywT, lyb, total);
    head_feats<<<B_, 512, 0, stream>>>(total, sf, w1, b1, w2, b2, aw1T, ab1, aw2, ab2, avar, (float*)d_out);
}

// Round 14
// 109.966 us; speedup vs baseline: 2.0326x; 1.2332x over previous
//
#include <hip/hip_runtime.h>
#include <hip/hip_fp8.h>
#include <math.h>

// Problem dims
#define S_   8
#define B_   16
#define D_   10
#define N_   32
#define E_   300
#define H_   128
#define G4_  512
#define SDIM_ 96
#define MID_ 256
#define TOT_ 528

typedef unsigned short u16;
typedef unsigned int u32;
typedef unsigned char u8;
typedef unsigned long long u64;
typedef __attribute__((ext_vector_type(8))) short short8;
typedef __attribute__((ext_vector_type(4))) float f32x4;

// round-to-nearest-even f32 -> bf16
static __device__ __forceinline__ u16 f2bf(float f) {
    unsigned u = __builtin_bit_cast(unsigned, f);
    return (u16)((u + 0x7FFFu + ((u >> 16) & 1u)) >> 16);
}
// f32 -> fp8 e4m3 (OCP)
static __device__ __forceinline__ u8 f2fp8(float f) {
    __hip_fp8_e4m3 t(f);
    return (u8)t.__x;
}

// fill one conv channel's LDS row (linear-k layout, kk = tap*300+e) from the
// original (e-major, tap-minor) f32 row. KT literal -> div by magic-mul.
template<int KT>
static __device__ __forceinline__ void fill_row(const float* __restrict__ src,
                                                u8* __restrict__ tilerow, int lane) {
    const float4* s4 = reinterpret_cast<const float4*>(src);
    for (int i4 = lane; i4 < 75 * KT; i4 += 64) {
        float4 v = s4[i4];
        float vv[4] = {v.x, v.y, v.z, v.w};
#pragma unroll
        for (int k = 0; k < 4; ++k) {
            int p = i4 * 4 + k;
            int e = p / KT, tap = p - e * KT;
            tilerow[tap * 300 + e] = f2fp8(vv[k] * 16.0f);
        }
    }
}

// ---------------------------------------------------------------------------
// prep v3 (1353 blocks x 256):
//  [0,640):    wpack3 fp8 x16: block = (s, cq of 4 channels); float4 fills,
//              literal-KT div, ks-parallel coalesced emit.
//  [640,896):  wpre2 bf16 (float4 fill).
//  [896,1352): 32x32 f32 transposes (lxwT/lywT/aw1T).
//  [1352]:     bcomb.
// ---------------------------------------------------------------------------
__global__ __launch_bounds__(256) void prep(
        const float* __restrict__ w3, const float* __restrict__ b3,
        const float* __restrict__ w4, const float* __restrict__ b4,
        const float* __restrict__ w5, const float* __restrict__ b5,
        const float* __restrict__ w_ih,
        const float* __restrict__ lxw, const float* __restrict__ lyw,
        const float* __restrict__ aw1,
        u8* __restrict__ wpack3, u16* __restrict__ wpre2,
        float* __restrict__ bcomb,
        float* __restrict__ lxwT, float* __restrict__ lywT,
        float* __restrict__ aw1T) {
    const int blk = blockIdx.x, tid = threadIdx.x;

    if (blk < 640) {                     // ---- wpack3 ----
        __shared__ u8 tile4[4][1504];
        const int s = blk / 80, cq = blk % 80;
        const int c0 = cq * 4;
        const int ch4 = tid >> 6, lane = tid & 63;
        for (int i = tid; i < 1504; i += 256)
            reinterpret_cast<u32*>(&tile4[0][0])[i] = 0u;
        __syncthreads();
        const int c = c0 + ch4;
        if (cq < 25)      fill_row<3>(w3 + (size_t)((s * 100 + c      ) * 300) * 3, &tile4[ch4][0], lane);
        else if (cq < 50) fill_row<4>(w4 + (size_t)((s * 100 + c - 100) * 300) * 4, &tile4[ch4][0], lane);
        else if (cq < 75) fill_row<5>(w5 + (size_t)((s * 100 + c - 200) * 300) * 5, &tile4[ch4][0], lane);
        __syncthreads();
        // emit: per ks this block owns bytes [ks*10240 + c0*32, +128) -> 32 u32
        u32* dst0 = reinterpret_cast<u32*>(wpack3) + (size_t)s * 120320;
        const int kss = tid >> 5, m = tid & 31;
        const int ch = m >> 3, b0 = (m & 7) * 4;
#pragma unroll
        for (int ksb = 0; ksb < 6; ++ksb) {
            int ks = ksb * 8 + kss;
            if (ks < 47) {
                int kk = ks * 32 + b0;
                u32 v = (u32)tile4[ch][kk] | ((u32)tile4[ch][kk + 1] << 8)
                      | ((u32)tile4[ch][kk + 2] << 16) | ((u32)tile4[ch][kk + 3] << 24);
                dst0[(size_t)ks * 2560 + cq * 32 + m] = v;
            }
        }
    } else if (blk < 896) {              // ---- wpre2 ----
        __shared__ u16 tile2[16][320];
        const int u = blk - 640, s = u >> 5, gg = u & 31;
        const int ch = tid >> 4, lane = tid & 15;
        const int g = gg * 16 + ch;
        const float4* src4 = reinterpret_cast<const float4*>(w_ih + (size_t)(s * 512 + g) * 300);
        for (int i4 = lane; i4 < 75; i4 += 16) {
            float4 v = src4[i4];
            tile2[ch][i4 * 4 + 0] = f2bf(v.x); tile2[ch][i4 * 4 + 1] = f2bf(v.y);
            tile2[ch][i4 * 4 + 2] = f2bf(v.z); tile2[ch][i4 * 4 + 3] = f2bf(v.w);
        }
        for (int p = 300 + lane; p < 320; p += 16) tile2[ch][p] = 0;
        __syncthreads();
        u32* dst0 = reinterpret_cast<u32*>(wpre2 + (size_t)s * 163840 + gg * 512);
        const int mch = tid >> 4, rem = (tid * 2) & 31;
        for (int ks = 0; ks < 10; ++ks) {
            u32 v = (u32)tile2[mch][ks * 32 + rem] | ((u32)tile2[mch][ks * 32 + rem + 1] << 16);
            dst0[(size_t)ks * 8192 + tid] = v;
        }
    } else if (blk < 1352) {             // ---- 32x32 transposes ----
        __shared__ float ldsT[32][33];
        const float* inp; float* outp;
        int inRS, outRS, i0, t0, ivalid = 32;
        if (blk < 1152) {                // lxwT (256 blocks)
            int u = blk - 896, s = u >> 5, t32 = u & 31;
            int it = t32 >> 2, tt = t32 & 3;
            inp = lxw + (size_t)s * 128 * 256; outp = lxwT + (size_t)s * 256 * 128;
            inRS = 256; outRS = 128; i0 = it * 32; t0 = tt * 32;
        } else if (blk < 1216) {         // lywT (64 blocks)
            int u = blk - 1152, s = u >> 3, t32 = u & 7;
            int it = t32 >> 1, tt = t32 & 1;
            inp = lyw + (size_t)s * 64 * 128; outp = lywT + (size_t)s * 128 * 64;
            inRS = 128; outRS = 64; i0 = it * 32; t0 = tt * 32;
        } else {                         // aw1T (136 blocks)
            int u = blk - 1216;
            int it = u >> 3, jt = u & 7;
            inp = aw1; outp = aw1T;
            inRS = 528; outRS = 256; i0 = it * 32; t0 = jt * 32;
            ivalid = (i0 + 32 <= 528) ? 32 : (528 - i0);
        }
        const int row = tid >> 3, cf = tid & 7;
        float4 v = make_float4(0.f, 0.f, 0.f, 0.f);
        if (cf * 4 < ivalid)
            v = *reinterpret_cast<const float4*>(inp + (size_t)(t0 + row) * inRS + i0 + cf * 4);
        ldsT[cf * 4 + 0][row] = v.x; ldsT[cf * 4 + 1][row] = v.y;
        ldsT[cf * 4 + 2][row] = v.z; ldsT[cf * 4 + 3][row] = v.w;
        __syncthreads();
        if (row < ivalid) {
            float4 w;
            w.x = ldsT[row][cf * 4 + 0]; w.y = ldsT[row][cf * 4 + 1];
            w.z = ldsT[row][cf * 4 + 2]; w.w = ldsT[row][cf * 4 + 3];
            *reinterpret_cast<float4*>(outp + (size_t)(i0 + row) * outRS + t0 + cf * 4) = w;
        }
    } else {                             // ---- bcomb ----
        for (int i = tid; i < 2560; i += 256) {
            int c = i % 320, s = i / 320;
            float bv = 0.f;
            if (c < 100)      bv = b3[s*100 + c];
            else if (c < 200) bv = b4[s*100 + c - 100];
            else if (c < 300) bv = b5[s*100 + c - 200];
            bcomb[i] = bv;
        }
    }
}

// ---------------------------------------------------------------------------
// conv via fp8 MFMA (unchanged from R13)
// ---------------------------------------------------------------------------
__global__ __launch_bounds__(512, 1) void conv_mfma(const float* __restrict__ news,
                                                    const u8* __restrict__ wpack3,
                                                    const float* __restrict__ bcomb,
                                                    u16* __restrict__ text_bf) {
    __shared__ u8 xs[5 * 10816];
    __shared__ float part[10][320];
    const int tid = threadIdx.x, bid = blockIdx.x;
    const int s = bid & 7, rr_ = bid >> 3, b = rr_ >> 1, half = rr_ & 1;
    const int l = tid & 63, wvi = tid >> 6;
    const int wm = wvi >> 2, wn = wvi & 3;
    const int q = l >> 4, r16 = l & 15;

    const u8* gp[5];
#pragma unroll
    for (int nt = 0; nt < 5; ++nt) {
        int c = wn * 80 + nt * 16 + r16;
        gp[nt] = wpack3 + (size_t)s * 481280 + c * 32 + q * 8;
    }

    u64 bf0[5], bf1[5];
#pragma unroll
    for (int nt = 0; nt < 5; ++nt) bf0[nt] = *reinterpret_cast<const u64*>(gp[nt]);
#pragma unroll
    for (int nt = 0; nt < 5; ++nt) bf1[nt] = *reinterpret_cast<const u64*>(gp[nt] + 10240);

    {
        const float4* xg = reinterpret_cast<const float4*>(
            news + (size_t)((b * 8 + s) * 10 + half * 5) * 9600);
        for (int base = 0; base < 12000; base += 4096) {
            float4 v[8];
#pragma unroll
            for (int j = 0; j < 8; ++j) {
                int idx = base + j * 512 + tid;
                if (idx < 12000) v[j] = xg[idx];
            }
#pragma unroll
            for (int j = 0; j < 8; ++j) {
                int idx = base + j * 512 + tid;
                if (idx < 12000) {
                    int day = idx / 2400, rem = idx - day * 2400;
                    u32 o = (u32)f2fp8(v[j].x) | ((u32)f2fp8(v[j].y) << 8)
                          | ((u32)f2fp8(v[j].z) << 16) | ((u32)f2fp8(v[j].w) << 24);
                    *reinterpret_cast<u32*>(&xs[day * 10816 + rem * 4]) = o;
                }
            }
        }
        for (int i = tid; i < 1520; i += 512) {
            int day = i / 304, p = i - day * 304;
            *reinterpret_cast<u32*>(&xs[day * 10816 + 9600 + p * 4]) = 0u;
        }
    }
    __syncthreads();

    f32x4 acc[5][5];
#pragma unroll
    for (int mt = 0; mt < 5; ++mt)
#pragma unroll
        for (int nt = 0; nt < 5; ++nt) acc[mt][nt] = (f32x4)(0.f);

#define LOADA(dst, ks) do {                                                       \
    _Pragma("unroll")                                                             \
    for (int mt_ = 0; mt_ < 5; ++mt_) {                                           \
        int di_ = wm * 5 + mt_;                                                   \
        int off_ = (di_ >> 1) * 10816 + (((di_ & 1) << 4) + r16) * 300            \
                   + (ks) * 32 + q * 8;                                           \
        u32 lo_ = *reinterpret_cast<const u32*>(&xs[off_]);                       \
        u32 hi_ = *reinterpret_cast<const u32*>(&xs[off_ + 4]);                   \
        dst[mt_] = (u64)lo_ | ((u64)hi_ << 32);                                   \
    } } while (0)

#define MFMAS(bfv, av) do {                                                       \
    _Pragma("unroll")                                                             \
    for (int nt_ = 0; nt_ < 5; ++nt_)                                             \
        _Pragma("unroll")                                                         \
        for (int mt_ = 0; mt_ < 5; ++mt_)                                         \
            acc[mt_][nt_] = __builtin_amdgcn_mfma_f32_16x16x32_fp8_fp8(          \
                (long long)av[mt_], (long long)bfv[nt_], acc[mt_][nt_], 0, 0, 0); \
    } while (0)

    for (int ks = 0; ks < 46; ks += 2) {
        u64 a0[5], a1[5];
        LOADA(a0, ks);
        MFMAS(bf0, a0);
#pragma unroll
        for (int nt = 0; nt < 5; ++nt)
            bf0[nt] = *reinterpret_cast<const u64*>(gp[nt] + (ks + 2) * 10240);

        LOADA(a1, ks + 1);
        MFMAS(bf1, a1);
        if (ks + 3 < 47) {
#pragma unroll
            for (int nt = 0; nt < 5; ++nt)
                bf1[nt] = *reinterpret_cast<const u64*>(gp[nt] + (ks + 3) * 10240);
        }
    }
    {
        u64 a0[5];
        LOADA(a0, 46);
        MFMAS(bf0, a0);
    }
#undef LOADA
#undef MFMAS

#pragma unroll
    for (int mt = 0; mt < 5; ++mt) {
        const int di = wm * 5 + mt;
        const int nwb = (di & 1) << 4;
#pragma unroll
        for (int nt = 0; nt < 5; ++nt) {
            int oc = wn * 80 + nt * 16 + r16;
            int L = (oc < 100) ? 30 : (oc < 200) ? 29 : 28;
            float mx = -3e38f;
#pragma unroll
            for (int rr = 0; rr < 4; ++rr) {
                int nw = nwb + q * 4 + rr;
                if (nw < L) mx = fmaxf(mx, acc[mt][nt][rr]);
            }
            mx = fmaxf(mx, __shfl_xor(mx, 16));
            mx = fmaxf(mx, __shfl_xor(mx, 32));
            if (l < 16) part[di][wn * 80 + nt * 16 + l] = mx;
        }
    }
    __syncthreads();
    for (int i = tid; i < 1600; i += 512) {
        int day = i / 320, oc = i - day * 320;
        float mx = fmaxf(part[2 * day][oc], part[2 * day + 1][oc]);
        text_bf[((size_t)(s * 16 + b) * 10 + half * 5 + day) * 320 + oc] =
            f2bf(mx * 0.0625f + bcomb[s * 320 + oc]);
    }
}

// ---------------------------------------------------------------------------
// stock_tail (R11 structure; XCD-pinned: s = bid&7 so all 16 same-s blocks
// land on one XCD -> weight set fetched once per XCD, not 8x)
// ---------------------------------------------------------------------------
__global__ __launch_bounds__(512) void stock_tail(const u16* __restrict__ text_bf,
                                                  const u16* __restrict__ wpre2,
                                                  const float* __restrict__ b_ih,
                                                  const float* __restrict__ b_hh,
                                                  const float* __restrict__ w_hh,
                                                  const float* __restrict__ lxwT, const float* __restrict__ lxb,
                                                  const float* __restrict__ lywT, const float* __restrict__ lyb,
                                                  float* __restrict__ total) {
    __shared__ u16 as16[16 * 320];
    __shared__ float pre_lds[D_][G4_];
    __shared__ float wchunk[128][129];
    __shared__ float h_lds[H_];
    __shared__ float gates[G4_];
    __shared__ float comb_l[256];
    __shared__ __align__(16) float hx[H_];
    const int sb = blockIdx.x;
    const int s = sb & 7, b = sb >> 3;     // XCD-pinned mapping
    const int t = threadIdx.x, l = t & 63, wv = t >> 6, q = l >> 4, r16 = l & 15;

    for (int i = t; i < 640; i += 512) {
        int r = i / 40, c = i % 40;
        float4 v = make_float4(0.f, 0.f, 0.f, 0.f);
        if (r < D_)
            v = *reinterpret_cast<const float4*>(
                text_bf + ((size_t)((s * 16 + b) * D_ + r)) * 320 + c * 8);
        *reinterpret_cast<float4*>(as16 + r * 320 + ((c ^ (r & 7)) << 3)) = v;
    }
    __syncthreads();

    {
        const u16* gpb[4];
#pragma unroll
        for (int nt = 0; nt < 4; ++nt) {
            int g = wv * 64 + nt * 16 + r16;
            gpb[nt] = wpre2 + (size_t)s * 163840 + g * 32 + q * 8;
        }
        f32x4 acc[4];
#pragma unroll
        for (int nt = 0; nt < 4; ++nt) acc[nt] = (f32x4)(0.f);
        for (int ks = 0; ks < 10; ++ks) {
            short8 a = *reinterpret_cast<const short8*>(
                as16 + r16 * 320 + (((ks * 4 + q) ^ (r16 & 7)) << 3));
#pragma unroll
            for (int nt = 0; nt < 4; ++nt) {
                short8 bf = *reinterpret_cast<const short8*>(gpb[nt] + ks * 16384);
                acc[nt] = __builtin_amdgcn_mfma_f32_16x16x32_bf16(a, bf, acc[nt], 0, 0, 0);
            }
        }
#pragma unroll
        for (int nt = 0; nt < 4; ++nt) {
            int g = wv * 64 + nt * 16 + r16;
            float bias = b_ih[s * G4_ + g] + b_hh[s * G4_ + g];
#pragma unroll
            for (int rr = 0; rr < 4; ++rr) {
                int row = q * 4 + rr;
                if (row < D_) pre_lds[row][g] = acc[nt][rr] + bias;
            }
        }
    }

    float wrs[128];
    for (int c = 0; c < 4; ++c) {
        __syncthreads();
        for (int i2 = t; i2 < 128 * 32; i2 += 512) {
            int row = i2 >> 5, fq = i2 & 31;
            float4 v = *reinterpret_cast<const float4*>(
                w_hh + ((size_t)(s * G4_ + c * 128 + row)) * H_ + fq * 4);
            wchunk[row][fq * 4 + 0] = v.x; wchunk[row][fq * 4 + 1] = v.y;
            wchunk[row][fq * 4 + 2] = v.z; wchunk[row][fq * 4 + 3] = v.w;
        }
        __syncthreads();
        if ((t >> 7) == c) {
            int r = t & 127;
#pragma unroll
            for (int i = 0; i < 128; ++i) wrs[i] = wchunk[r][i];
        }
    }
    __syncthreads();

    float cc = 0.f, hsum = 0.f, hval = 0.f;
    if (t < H_) h_lds[t] = 0.f;
    __syncthreads();

    for (int d = 0; d < D_; ++d) {
        float a0 = pre_lds[d][t];
        float a1 = 0.f, a2 = 0.f, a3 = 0.f;
#pragma unroll
        for (int i = 0; i < 128; i += 4) {
            float4 h4 = *reinterpret_cast<const float4*>(&h_lds[i]);
            a0 = fmaf(wrs[i + 0], h4.x, a0);
            a1 = fmaf(wrs[i + 1], h4.y, a1);
            a2 = fmaf(wrs[i + 2], h4.z, a2);
            a3 = fmaf(wrs[i + 3], h4.w, a3);
        }
        gates[t] = (a0 + a1) + (a2 + a3);
        __syncthreads();
        if (t < H_) {
            float ig = 1.f / (1.f + expf(-gates[t]));
            float fg = 1.f / (1.f + expf(-gates[H_ + t]));
            float gg = tanhf(gates[2 * H_ + t]);
            float og = 1.f / (1.f + expf(-gates[3 * H_ + t]));
            cc = fg * cc + ig * gg;
            hval = og * tanhf(cc);
            hsum += hval;
            h_lds[t] = hval;
        }
        __syncthreads();
    }
    if (t < H_) { comb_l[t] = hval; comb_l[H_ + t] = hsum; }
    __syncthreads();
    if (t < H_) {
        const float* wvp = lxwT + (size_t)s * 256 * 128 + t;
        float a0 = lxb[s * H_ + t], a1 = 0.f;
        for (int i = 0; i < 256; i += 2) {
            a0 = fmaf(comb_l[i], wvp[(size_t)i * 128], a0);
            a1 = fmaf(comb_l[i + 1], wvp[(size_t)(i + 1) * 128], a1);
        }
        hx[t] = fmaxf(a0 + a1, 0.f);
    }
    __syncthreads();
    if (t < 64) {
        const float* wvp = lywT + (size_t)s * 128 * 64 + t;
        float a0 = lyb[s * 64 + t], a1 = 0.f;
        for (int i = 0; i < 128; i += 2) {
            a0 = fmaf(hx[i], wvp[(size_t)i * 64], a0);
            a1 = fmaf(hx[i + 1], wvp[(size_t)(i + 1) * 64], a1);
        }
        total[(size_t)b * 512 + s * 64 + t] = fmaxf(a0 + a1, 0.f);
    }
}

// ---------------------------------------------------------------------------
// head_feats (unchanged)
// ---------------------------------------------------------------------------
__global__ __launch_bounds__(512) void head_feats(const float* __restrict__ total,
                                                  const float* __restrict__ sf,
                                                  const float* __restrict__ w1, const float* __restrict__ b1,
                                                  const float* __restrict__ w2, const float* __restrict__ b2,
                                                  const float* __restrict__ aw1T, const float* __restrict__ ab1,
                                                  const float* __restrict__ aw2, const float* __restrict__ ab2,
                                                  const float* __restrict__ avar,
                                                  float* __restrict__ out) {
    __shared__ __align__(16) float tr[TOT_];
    __shared__ float hid[MID_];
    __shared__ float h1f[24];
    __shared__ float pA[MID_], pB[MID_];
    const int bb = blockIdx.x, t = threadIdx.x;
    if (t < 128)
        reinterpret_cast<float4*>(tr)[t] = reinterpret_cast<const float4*>(total + (size_t)bb * 512)[t];
    if (t < 24) {
        float acc = b1[t];
        for (int i = 0; i < SDIM_; ++i) acc = fmaf(sf[bb * SDIM_ + i], w1[t * SDIM_ + i], acc);
        h1f[t] = fmaxf(acc, 0.f);
    }
    __syncthreads();
    if (t < 16) {
        float acc = b2[t];
        for (int i = 0; i < 24; ++i) acc = fmaf(h1f[i], w2[t * 24 + i], acc);
        tr[512 + t] = acc;
    }
    __syncthreads();
    {
        const int j = t & 255, hf = t >> 8;
        const int ilo = hf ? 264 : 0, ihi = hf ? 528 : 264;
        const float* wv = aw1T + j;
        float a0 = 0.f, a1 = 0.f, a2 = 0.f, a3 = 0.f;
        for (int i = ilo; i < ihi; i += 4) {
            a0 = fmaf(tr[i + 0], wv[(size_t)(i + 0) * 256], a0);
            a1 = fmaf(tr[i + 1], wv[(size_t)(i + 1) * 256], a1);
            a2 = fmaf(tr[i + 2], wv[(size_t)(i + 2) * 256], a2);
            a3 = fmaf(tr[i + 3], wv[(size_t)(i + 3) * 256], a3);
        }
        float p = (a0 + a1) + (a2 + a3);
        if (hf) pB[j] = p; else pA[j] = p;
    }
    __syncthreads();
    if (t < MID_) hid[t] = fmaxf(pA[t] + pB[t] + ab1[t], 0.f);
    __syncthreads();
    if (t < 8) {
        float acc = ab2[t];
        const float* wv = aw2 + (size_t)t * MID_;
        for (int i = 0; i < MID_; ++i) acc = fmaf(hid[i], wv[i], acc);
        out[bb * 8 + t] = tanhf(acc);
    }
    if (bb == 0 && t >= 8 && t < 16) out[128 + (t - 8)] = expf(avar[t - 8]);
}

// ---------------------------------------------------------------------------
extern "C" void kernel_launch(void* const* d_in, const int* in_sizes, int n_in,
                              void* d_out, int out_size, void* d_ws, size_t ws_size,
                              hipStream_t stream) {
    const float* news = (const float*)d_in[0];
    const float* sf   = (const float*)d_in[1];
    const float* w3   = (const float*)d_in[2];  const float* b3 = (const float*)d_in[3];
    const float* w4   = (const float*)d_in[4];  const float* b4 = (const float*)d_in[5];
    const float* w5   = (const float*)d_in[6];  const float* b5 = (const float*)d_in[7];
    const float* w_ih = (const float*)d_in[8];  const float* w_hh = (const float*)d_in[9];
    const float* b_ih = (const float*)d_in[10]; const float* b_hh = (const float*)d_in[11];
    const float* lxw  = (const float*)d_in[12]; const float* lxb = (const float*)d_in[13];
    const float* lyw  = (const float*)d_in[14]; const float* lyb = (const float*)d_in[15];
    const float* w1   = (const float*)d_in[16]; const float* b1 = (const float*)d_in[17];
    const float* w2   = (const float*)d_in[18]; const float* b2 = (const float*)d_in[19];
    const float* aw1  = (const float*)d_in[20]; const float* ab1 = (const float*)d_in[21];
    const float* aw2  = (const float*)d_in[22]; const float* ab2 = (const float*)d_in[23];
    const float* avar = (const float*)d_in[24];

    char* ws = (char*)d_ws;
    u8*    wpack3  = (u8*)ws;                                   // 3,850,240 B
    u16*   wpre2   = (u16*)(ws + 3850240);                      // 2,621,440 B
    float* bcomb   = (float*)(ws + 6471680);                    // 10,240 B
    u16*   text_bf = (u16*)(ws + 6481920);                      // 819,200 B
    float* total   = (float*)(ws + 7301120);                    // 32,768 B
    float* lxwT    = (float*)(ws + 7333888);                    // 1,048,576 B
    float* lywT    = (float*)(ws + 8382464);                    // 262,144 B
    float* aw1T    = (float*)(ws + 8644608);                    // 540,672 B (end ~9.2 MB)

    prep<<<1353, 256, 0, stream>>>(w3, b3, w4, b4, w5, b5, w_ih, lxw, lyw, aw1,
                                   wpack3, wpre2, bcomb, lxwT, lywT, aw1T);
    conv_mfma<<<256, 512, 0, stream>>>(news, wpack3, bcomb, text_bf);
    stock_tail<<<S_ * B_, 512, 0, stream>>>(text_bf, wpre2, b_ih, b_hh, w_hh,
                                            lxwT, lxb, lywT, lyb, total);
    head_feats<<<B_, 512, 0, stream>>>(total, sf, w1, b1, w2, b2, aw1T, ab1, aw2, ab2, avar, (float*)d_out);
}